// Round 4
// baseline (518.359 us; speedup 1.0000x reference)
//
#include <hip/hip_runtime.h>
#include <cstdint>
#include <cstddef>

#define NN 50000
#define NE 200000
#define IND 768
#define HID 256
#define OUTD 64
#define NB 196  // ceil(NN/256)

typedef __bf16 bf16;
typedef __bf16 bf16x8 __attribute__((ext_vector_type(8)));
typedef float f32x4 __attribute__((ext_vector_type(4)));

// async global->LDS, 16B per lane; lds base must be wave-uniform (lane i lands at base + i*16)
__device__ __forceinline__ void ld_lds16(const void* g, void* l) {
  __builtin_amdgcn_global_load_lds((const __attribute__((address_space(1))) void*)g,
                                   (__attribute__((address_space(3))) void*)l, 16, 0, 0);
}

// ---------------- edge prep: last-write-wins index + dst histogram ----------------
__global__ __launch_bounds__(256) void k_edge_prep(const int* __restrict__ ei,
                                                   int* __restrict__ le, int* __restrict__ deg) {
  int e = blockIdx.x * 256 + threadIdx.x;
  if (e < NE) {
    atomicMax(&le[ei[e]], e);
    atomicAdd(&deg[ei[NE + e]], 1);
  }
}

// ---------------- CSR build ----------------
__global__ __launch_bounds__(256) void k_scan_block(const int* __restrict__ deg,
                                                    int* __restrict__ excl, int* __restrict__ bsum) {
  __shared__ int sm[256];
  int tid = threadIdx.x;
  int i = blockIdx.x * 256 + tid;
  int v = (i < NN) ? deg[i] : 0;
  sm[tid] = v;
  __syncthreads();
#pragma unroll
  for (int off = 1; off < 256; off <<= 1) {
    int t = (tid >= off) ? sm[tid - off] : 0;
    __syncthreads();
    sm[tid] += t;
    __syncthreads();
  }
  if (i < NN) excl[i] = sm[tid] - v;
  if (tid == 255) bsum[blockIdx.x] = sm[255];
}

__global__ __launch_bounds__(256) void k_scan_partials(const int* __restrict__ bsum,
                                                       int* __restrict__ bbase) {
  __shared__ int sm[256];
  int tid = threadIdx.x;
  int v = (tid < NB) ? bsum[tid] : 0;
  sm[tid] = v;
  __syncthreads();
#pragma unroll
  for (int off = 1; off < 256; off <<= 1) {
    int t = (tid >= off) ? sm[tid - off] : 0;
    __syncthreads();
    sm[tid] += t;
    __syncthreads();
  }
  bbase[tid] = sm[tid] - v;
}

// also computes tmod[i] = etype of last incident src-edge (or -1)
__global__ __launch_bounds__(256) void k_add_base(const int* __restrict__ excl,
                                                  const int* __restrict__ bbase,
                                                  const int* __restrict__ le,
                                                  const int* __restrict__ et,
                                                  int* __restrict__ rowstart, int* __restrict__ cur,
                                                  int* __restrict__ tmod) {
  int i = blockIdx.x * 256 + threadIdx.x;
  if (i < NN) {
    int rs = excl[i] + bbase[i >> 8];
    rowstart[i] = rs;
    cur[i] = rs;
    int l = le[i];
    tmod[i] = (l >= 0) ? et[l] : -1;
  }
}

__global__ __launch_bounds__(256) void k_scatter_csr(const int* __restrict__ ei,
                                                     int* __restrict__ cur, int* __restrict__ csr) {
  int e = blockIdx.x * 256 + threadIdx.x;
  if (e < NE) {
    int d = ei[NE + e];
    int pos = atomicAdd(&cur[d], 1);
    csr[pos] = ei[e];
  }
}

// ---------------- prep: W1t, W2t (bf16 transposes) + P = emb @ W1 (fp32) ----------------
// grid 768 + 64 + 6 = 838 blocks
__global__ __launch_bounds__(256) void k_prep(const float* __restrict__ W1,
                                              const float* __restrict__ W2,
                                              const float* __restrict__ eemb,
                                              bf16* __restrict__ W1t,
                                              bf16* __restrict__ W2t,
                                              float* __restrict__ P) {
  int b = blockIdx.x, tid = threadIdx.x;
  if (b < 768) {                       // W1 [768][256] -> W1t [256][768]
    int k = b, n = tid;
    W1t[n * 768 + k] = (bf16)W1[k * 256 + n];
  } else if (b < 768 + 64) {           // W2 [256][64] -> W2t [64][256]
    int k = (b - 768) * 4 + (tid >> 6);
    int n = tid & 63;
    W2t[n * 256 + k] = (bf16)W2[k * 64 + n];
  } else {                             // P[r][c] = sum_k emb[r][k] * W1[k][c]
    int r = b - 832, c = tid;
    float s = 0.f;
    for (int k = 0; k < 768; k++) s += eemb[r * 768 + k] * W1[k * 256 + c];
    P[r * 256 + c] = s;
  }
}

// ---------------- GEMM1: h1 = bf16(x) @ W1t^T + P[tmod], fused logits ----------------
// 128x128 tile, BK=32, waves 2x2 (64x64 each). A fp32 via async global_load_lds
// into XOR-swizzled LDS; converted to bf16 at frag read.
__global__ __launch_bounds__(256) void k_gemm1(const float* __restrict__ Ax,
                                               const bf16* __restrict__ Bt,
                                               const int* __restrict__ tmod,
                                               const float* __restrict__ P,
                                               bf16* __restrict__ C,
                                               const float* __restrict__ aS,
                                               const float* __restrict__ aD,
                                               float* __restrict__ alS,
                                               float* __restrict__ alD) {
  __shared__ float As[128 * 32];  // 16 KB; chunk swizzle: lds chunk c holds global chunk c^(row&7)
  __shared__ bf16 Bs[128 * 32];   // 8 KB;  lds chunk c holds global chunk c^((row>>1)&3)
  const int tid = threadIdx.x, lane = tid & 63, wave = tid >> 6;
  const int wr = wave >> 1, wc = wave & 1;
  const int ln15 = lane & 15, q = lane >> 4;
  const int n0 = blockIdx.x * 128, m0 = blockIdx.y * 128;

  const int a_lrow = lane >> 3, a_gch = (lane & 7) ^ a_lrow;          // A: 8 rows/instr
  const int b_lrow = lane >> 2, b_gch = (lane & 3) ^ ((b_lrow >> 1) & 3);  // B: 16 rows/instr

  f32x4 acc[4][4] = {};

  for (int kt = 0; kt < IND; kt += 32) {
    __syncthreads();  // prev ds_reads done before overwrite
#pragma unroll
    for (int j = 0; j < 4; j++) {
      int g = wave * 4 + j;                       // row group g: rows g*8..g*8+7
      int grow = min(m0 + g * 8 + a_lrow, NN - 1);
      ld_lds16(Ax + (size_t)grow * IND + kt + a_gch * 4, As + g * 256);
    }
#pragma unroll
    for (int j = 0; j < 2; j++) {
      int h = wave * 2 + j;                       // row group h: rows h*16..h*16+15
      int grow = h * 16 + b_lrow;                 // HID=256 exact, no clamp needed
      ld_lds16(Bt + (size_t)(n0 + grow) * IND + kt + b_gch * 8, Bs + h * 512);
    }
    __syncthreads();  // drains vmcnt -> LDS data visible

    bf16x8 af[4], bfr[4];
    const float4* Asv = (const float4*)As;
#pragma unroll
    for (int mi = 0; mi < 4; mi++) {
      int R = wr * 64 + mi * 16 + ln15, msk = R & 7;
      float4 f0 = Asv[R * 8 + ((2 * q) ^ msk)];
      float4 f1 = Asv[R * 8 + ((2 * q + 1) ^ msk)];
      bf16x8 t;
      t[0] = (bf16)f0.x; t[1] = (bf16)f0.y; t[2] = (bf16)f0.z; t[3] = (bf16)f0.w;
      t[4] = (bf16)f1.x; t[5] = (bf16)f1.y; t[6] = (bf16)f1.z; t[7] = (bf16)f1.w;
      af[mi] = t;
    }
#pragma unroll
    for (int ni = 0; ni < 4; ni++) {
      int R = wc * 64 + ni * 16 + ln15;
      int c = q ^ ((R >> 1) & 3);
      bfr[ni] = *(const bf16x8*)(Bs + R * 32 + c * 8);
    }
#pragma unroll
    for (int mi = 0; mi < 4; mi++)
#pragma unroll
      for (int ni = 0; ni < 4; ni++)
        acc[mi][ni] = __builtin_amdgcn_mfma_f32_16x16x32_bf16(af[mi], bfr[ni], acc[mi][ni], 0, 0, 0);
  }

  // epilogue: add P[tmod[row]], store bf16 C, and emit per-head logits
  const int hd = (n0 + wc * 64) >> 6;
#pragma unroll
  for (int mi = 0; mi < 4; mi++) {
#pragma unroll
    for (int r = 0; r < 4; r++) {
      int row = m0 + wr * 64 + mi * 16 + q * 4 + r;
      bool vr = row < NN;
      int t = tmod[vr ? row : NN - 1];
      float ps = 0.f, pd = 0.f;
#pragma unroll
      for (int ni = 0; ni < 4; ni++) {
        int col = n0 + wc * 64 + ni * 16 + ln15;
        float val = acc[mi][ni][r];
        if (t >= 0) val += P[t * HID + col];
        ps += val * aS[col];
        pd += val * aD[col];
        if (vr) C[(size_t)row * HID + col] = (bf16)val;
      }
#pragma unroll
      for (int o = 1; o < 16; o <<= 1) { ps += __shfl_xor(ps, o); pd += __shfl_xor(pd, o); }
      if (ln15 == 0 && vr) { alS[row * 4 + hd] = ps; alD[row * 4 + hd] = pd; }
    }
  }
}

// ---------------- GEMM2: h2 = hln @ W2t^T, fused logits. 128x64 tile, waves 4x1 ----------------
__global__ __launch_bounds__(256) void k_gemm2(const bf16* __restrict__ A,
                                               const bf16* __restrict__ Bt,
                                               float* __restrict__ C,
                                               const float* __restrict__ aS,
                                               const float* __restrict__ aD,
                                               float* __restrict__ alS,
                                               float* __restrict__ alD) {
  __shared__ bf16 As[128 * 32];  // 8 KB
  __shared__ bf16 Bs[64 * 32];   // 4 KB
  const int tid = threadIdx.x, lane = tid & 63, wave = tid >> 6;
  const int ln15 = lane & 15, q = lane >> 4;
  const int m0 = blockIdx.x * 128;
  const int b_lrow = lane >> 2, b_gch = (lane & 3) ^ ((b_lrow >> 1) & 3);

  f32x4 acc[2][4] = {};

  for (int kt = 0; kt < HID; kt += 32) {
    __syncthreads();
#pragma unroll
    for (int j = 0; j < 2; j++) {
      int h = wave * 2 + j;  // rows h*16..+15 of A tile
      int grow = min(m0 + h * 16 + b_lrow, NN - 1);
      ld_lds16(A + (size_t)grow * HID + kt + b_gch * 8, As + h * 512);
    }
    {
      int grow = wave * 16 + b_lrow;  // B rows 0..63 exact
      ld_lds16(Bt + (size_t)grow * HID + kt + b_gch * 8, Bs + wave * 512);
    }
    __syncthreads();

    bf16x8 af[2], bfr[4];
#pragma unroll
    for (int mi = 0; mi < 2; mi++) {
      int R = wave * 32 + mi * 16 + ln15;
      int c = q ^ ((R >> 1) & 3);
      af[mi] = *(const bf16x8*)(As + R * 32 + c * 8);
    }
#pragma unroll
    for (int ni = 0; ni < 4; ni++) {
      int R = ni * 16 + ln15;
      int c = q ^ ((R >> 1) & 3);
      bfr[ni] = *(const bf16x8*)(Bs + R * 32 + c * 8);
    }
#pragma unroll
    for (int mi = 0; mi < 2; mi++)
#pragma unroll
      for (int ni = 0; ni < 4; ni++)
        acc[mi][ni] = __builtin_amdgcn_mfma_f32_16x16x32_bf16(af[mi], bfr[ni], acc[mi][ni], 0, 0, 0);
  }

#pragma unroll
  for (int mi = 0; mi < 2; mi++) {
#pragma unroll
    for (int r = 0; r < 4; r++) {
      int row = m0 + wave * 32 + mi * 16 + q * 4 + r;
      bool vr = row < NN;
      float ps = 0.f, pd = 0.f;
#pragma unroll
      for (int ni = 0; ni < 4; ni++) {
        int col = ni * 16 + ln15;
        float val = acc[mi][ni][r];
        ps += val * aS[col];
        pd += val * aD[col];
        if (vr) C[(size_t)row * OUTD + col] = val;
      }
#pragma unroll
      for (int o = 1; o < 16; o <<= 1) { ps += __shfl_xor(ps, o); pd += __shfl_xor(pd, o); }
      if (ln15 == 0 && vr) { alS[row] = ps; alD[row] = pd; }
    }
  }
}

// ---------------- fused gather-aggregate + LN + ELU, layer 1 (8-way chunked MLP) ----------------
__global__ __launch_bounds__(256) void k_agg_ln1(const int* __restrict__ rowstart,
                                                 const int* __restrict__ deg,
                                                 const int* __restrict__ csr,
                                                 const bf16* __restrict__ h1,
                                                 const float* __restrict__ alS,
                                                 const float* __restrict__ alD,
                                                 const float* __restrict__ b1,
                                                 const float* __restrict__ g1,
                                                 const float* __restrict__ be1,
                                                 bf16* __restrict__ hln) {
  __shared__ float red[8];
  int n = blockIdx.x, f = threadIdx.x, hd = f >> 6;
  int start = rowstart[n], cnt = deg[n];
  float ald = alD[n * 4 + hd];
  float accv = 0.f, accw = 0.f;
  for (int j0 = 0; j0 < cnt; j0 += 8) {
    int m = cnt - j0; m = m > 8 ? 8 : m;
    int sj[8]; float wv[8];
#pragma unroll
    for (int jj = 0; jj < 8; jj++) sj[jj] = (jj < m) ? csr[start + j0 + jj] : 0;
#pragma unroll
    for (int jj = 0; jj < 8; jj++) {
      float lg = alS[sj[jj] * 4 + hd] + ald;
      lg = lg >= 0.f ? lg : 0.2f * lg;
      wv[jj] = (jj < m) ? __expf(lg) : 0.f;  // shift-free softmax: logits bounded
    }
#pragma unroll
    for (int jj = 0; jj < 8; jj++) {
      accv += wv[jj] * (float)h1[(size_t)sj[jj] * HID + f];
      accw += wv[jj];
    }
  }
  float v = (cnt > 0) ? accv / accw : 0.f;
  v += b1[f];
  float s = v, ss = v * v;
#pragma unroll
  for (int off = 32; off; off >>= 1) { s += __shfl_xor(s, off); ss += __shfl_xor(ss, off); }
  if ((f & 63) == 0) { red[f >> 6] = s; red[4 + (f >> 6)] = ss; }
  __syncthreads();
  float tot = red[0] + red[1] + red[2] + red[3];
  float tss = red[4] + red[5] + red[6] + red[7];
  float mu = tot * (1.f / HID);
  float var = tss * (1.f / HID) - mu * mu;
  float y = (v - mu) * rsqrtf(var + 1e-5f) * g1[f] + be1[f];
  y = y > 0.f ? y : __expf(y) - 1.f;  // ELU
  hln[(size_t)n * HID + f] = (bf16)y;
}

// ---------------- fused gather-aggregate + LN, layer 2 (4 nodes/block, chunked) ----------------
__global__ __launch_bounds__(256) void k_agg_ln2(const int* __restrict__ rowstart,
                                                 const int* __restrict__ deg,
                                                 const int* __restrict__ csr,
                                                 const float* __restrict__ h2,
                                                 const float* __restrict__ alS,
                                                 const float* __restrict__ alD,
                                                 const float* __restrict__ b2,
                                                 const float* __restrict__ g2,
                                                 const float* __restrict__ be2,
                                                 float* __restrict__ out) {
  int n = blockIdx.x * 4 + (threadIdx.x >> 6);
  int f = threadIdx.x & 63;
  int start = rowstart[n], cnt = deg[n];
  float ald = alD[n];
  float accv = 0.f, accw = 0.f;
  for (int j0 = 0; j0 < cnt; j0 += 8) {
    int m = cnt - j0; m = m > 8 ? 8 : m;
    int sj[8]; float wv[8];
#pragma unroll
    for (int jj = 0; jj < 8; jj++) sj[jj] = (jj < m) ? csr[start + j0 + jj] : 0;
#pragma unroll
    for (int jj = 0; jj < 8; jj++) {
      float lg = alS[sj[jj]] + ald;
      lg = lg >= 0.f ? lg : 0.2f * lg;
      wv[jj] = (jj < m) ? __expf(lg) : 0.f;
    }
#pragma unroll
    for (int jj = 0; jj < 8; jj++) {
      accv += wv[jj] * h2[(size_t)sj[jj] * OUTD + f];
      accw += wv[jj];
    }
  }
  float v = (cnt > 0) ? accv / accw : 0.f;
  v += b2[f];
  float s = v, ss = v * v;
#pragma unroll
  for (int off = 32; off; off >>= 1) { s += __shfl_xor(s, off); ss += __shfl_xor(ss, off); }
  float mu = s * (1.f / OUTD);
  float var = ss * (1.f / OUTD) - mu * mu;
  out[(size_t)n * OUTD + f] = (v - mu) * rsqrtf(var + 1e-5f) * g2[f] + be2[f];
}

extern "C" void kernel_launch(void* const* d_in, const int* in_sizes, int n_in,
                              void* d_out, int out_size, void* d_ws, size_t ws_size,
                              hipStream_t stream) {
  const float* x    = (const float*)d_in[0];
  const int*   ei   = (const int*)d_in[1];
  const int*   et   = (const int*)d_in[2];
  const float* eemb = (const float*)d_in[3];
  const float* W1   = (const float*)d_in[4];
  const float* as1  = (const float*)d_in[5];
  const float* ad1  = (const float*)d_in[6];
  const float* b1   = (const float*)d_in[7];
  const float* g1   = (const float*)d_in[8];
  const float* be1  = (const float*)d_in[9];
  const float* W2   = (const float*)d_in[10];
  const float* as2  = (const float*)d_in[11];
  const float* ad2  = (const float*)d_in[12];
  const float* b2   = (const float*)d_in[13];
  const float* g2   = (const float*)d_in[14];
  const float* be2  = (const float*)d_in[15];
  float* out = (float*)d_out;

  char* base = (char*)d_ws;
  size_t off = 0;
  auto alloc = [&](size_t bytes) -> void* {
    void* p = base + off;
    off = (off + bytes + 255) & ~(size_t)255;
    return p;
  };
  int*   le    = (int*)alloc((size_t)NN * 4);
  int*   deg   = (int*)alloc((size_t)NN * 4);
  int*   excl  = (int*)alloc((size_t)NN * 4);
  int*   bsum  = (int*)alloc(256 * 4);
  int*   bbase = (int*)alloc(256 * 4);
  int*   rowst = (int*)alloc((size_t)NN * 4);
  int*   cur   = (int*)alloc((size_t)NN * 4);
  int*   tmod  = (int*)alloc((size_t)NN * 4);
  int*   csr   = (int*)alloc((size_t)NE * 4);
  bf16*  h1    = (bf16*)alloc((size_t)NN * HID * 2);
  float* alS1  = (float*)alloc((size_t)NN * 4 * 4);
  float* alD1  = (float*)alloc((size_t)NN * 4 * 4);
  bf16*  hln   = (bf16*)alloc((size_t)NN * HID * 2);
  float* h2    = (float*)alloc((size_t)NN * OUTD * 4);
  float* alS2  = (float*)alloc((size_t)NN * 4);
  float* alD2  = (float*)alloc((size_t)NN * 4);
  bf16*  W1t   = (bf16*)alloc((size_t)HID * IND * 2);
  bf16*  W2t   = (bf16*)alloc((size_t)OUTD * HID * 2);
  float* P     = (float*)alloc(6 * HID * 4);

  hipMemsetAsync(le, 0xFF, (size_t)NN * 4, stream);  // -1
  hipMemsetAsync(deg, 0, (size_t)NN * 4, stream);

  // CSR + last-edge prep
  k_edge_prep<<<(NE + 255) / 256, 256, 0, stream>>>(ei, le, deg);
  k_scan_block<<<NB, 256, 0, stream>>>(deg, excl, bsum);
  k_scan_partials<<<1, 256, 0, stream>>>(bsum, bbase);
  k_add_base<<<NB, 256, 0, stream>>>(excl, bbase, le, et, rowst, cur, tmod);
  k_scatter_csr<<<(NE + 255) / 256, 256, 0, stream>>>(ei, cur, csr);

  // weights + P
  k_prep<<<838, 256, 0, stream>>>(W1, W2, eemb, W1t, W2t, P);

  // layer 1
  k_gemm1<<<dim3(2, (NN + 127) / 128), 256, 0, stream>>>(x, W1t, tmod, P, h1, as1, ad1, alS1, alD1);
  k_agg_ln1<<<NN, 256, 0, stream>>>(rowst, deg, csr, h1, alS1, alD1, b1, g1, be1, hln);

  // layer 2
  k_gemm2<<<(NN + 127) / 128, 256, 0, stream>>>(hln, W2t, h2, as2, ad2, alS2, alD2);
  k_agg_ln2<<<NN / 4, 256, 0, stream>>>(rowst, deg, csr, h2, alS2, alD2, b2, g2, be2, out);
}